// Round 8
// baseline (369.089 us; speedup 1.0000x reference)
//
#include <hip/hip_runtime.h>
#include <cstdint>
#include <cstddef>

#define NHEADS 16
#define DHEAD 64
#define BATCH 4
#define SEQ 2048
// M = 8192, D = 1024

typedef __attribute__((ext_vector_type(8))) __bf16 bf16x8;
typedef __attribute__((ext_vector_type(4))) float f32x4;

__device__ __forceinline__ unsigned short f2bf(float f) {
  union { float f; unsigned u; } v; v.f = f;
  unsigned r = v.u + 0x7FFFu + ((v.u >> 16) & 1u);  // RNE
  return (unsigned short)(r >> 16);
}

__device__ __forceinline__ ushort4 cvt4(float4 f) {
  ushort4 o;
  o.x = f2bf(f.x); o.y = f2bf(f.y); o.z = f2bf(f.z); o.w = f2bf(f.w);
  return o;
}

// ---------------- f32 -> bf16 convert (x4 vectorized) ----------------
__global__ void cvt_bf16(const float* __restrict__ in, unsigned short* __restrict__ out, int n4) {
  int i = blockIdx.x * blockDim.x + threadIdx.x;
  int stride = gridDim.x * blockDim.x;
  for (; i < n4; i += stride) {
    float4 f = ((const float4*)in)[i];
    ((ushort4*)out)[i] = cvt4(f);
  }
}

// ---------------- QKV GEMM: bf16 xb [8192,1024] @ f32 w_qkv [3072,1024]^T + bias ----------------
// 128x128 tile, BK=32. A-side staged via global_load_lds (async DMA, no registers);
// B-side f32 loads + cvt + ds_write, all INSIDE the barrier window (zero cross-barrier VGPRs
// -> no spill; rounds 5/6 showed register prefetch spills ~800MB scratch regardless of bounds).
__global__ __launch_bounds__(256, 2) void gemm_qkv(
    const unsigned short* __restrict__ A,    // xb bf16 [8192][1024]
    const float* __restrict__ Bw,            // w_qkv f32 [3072][1024]
    const float* __restrict__ bias,          // [3072]
    unsigned short* __restrict__ qb,         // [64][2048][64]  (q pre-scaled by 1/8)
    unsigned short* __restrict__ kb,         // [64][2048][64]
    unsigned short* __restrict__ vt) {       // [64][64][2048]  (V^T)
  __shared__ unsigned short As[128 * 32];    // unpadded: DMA dest = base + lane*16B
  __shared__ unsigned short Bs[128 * 32];
  const int t = threadIdx.x;
  const int lane = t & 63;
  const int wv = t >> 6;
  const int wm = wv >> 1, wn = wv & 1;
  const int quad = lane >> 4, l15 = lane & 15;
  const int bM = blockIdx.y * 128;
  const int bN = blockIdx.x * 128;
  const int r0 = t >> 2;        // 0..63
  const int c0 = (t & 3) * 8;   // 0,8,16,24

  f32x4 acc[4][4];
#pragma unroll
  for (int i = 0; i < 4; i++)
#pragma unroll
    for (int j = 0; j < 4; j++) acc[i][j] = f32x4{0.f, 0.f, 0.f, 0.f};

  const unsigned short* aS0 = A + (size_t)(bM + r0) * 1024 + c0;        // + k0
  const unsigned short* aS1 = A + (size_t)(bM + 64 + r0) * 1024 + c0;
  const size_t bR0 = (size_t)(bN + r0) * 1024 + c0;
  const size_t bR1 = (size_t)(bN + 64 + r0) * 1024 + c0;

  for (int kt = 0; kt < 32; ++kt) {
    const int k0 = kt * 32;
    __syncthreads();  // previous iteration's LDS readers done
    __builtin_amdgcn_global_load_lds(
        (const __attribute__((address_space(1))) void*)(aS0 + k0),
        (__attribute__((address_space(3))) void*)(&As[r0 * 32 + c0]), 16, 0, 0);
    __builtin_amdgcn_global_load_lds(
        (const __attribute__((address_space(1))) void*)(aS1 + k0),
        (__attribute__((address_space(3))) void*)(&As[(64 + r0) * 32 + c0]), 16, 0, 0);
    float4 b00 = *(const float4*)&Bw[bR0 + k0];
    float4 b01 = *(const float4*)&Bw[bR0 + k0 + 4];
    float4 b10 = *(const float4*)&Bw[bR1 + k0];
    float4 b11 = *(const float4*)&Bw[bR1 + k0 + 4];
    *(ushort4*)&Bs[r0 * 32 + c0] = cvt4(b00);
    *(ushort4*)&Bs[r0 * 32 + c0 + 4] = cvt4(b01);
    *(ushort4*)&Bs[(64 + r0) * 32 + c0] = cvt4(b10);
    *(ushort4*)&Bs[(64 + r0) * 32 + c0 + 4] = cvt4(b11);
    __syncthreads();  // drains DMA (vmcnt) + LDS writes (lgkm)

    bf16x8 af[4], bf[4];
#pragma unroll
    for (int mi = 0; mi < 4; mi++)
      af[mi] = *(const bf16x8*)&As[(wm * 64 + mi * 16 + l15) * 32 + quad * 8];
#pragma unroll
    for (int ni = 0; ni < 4; ni++)
      bf[ni] = *(const bf16x8*)&Bs[(wn * 64 + ni * 16 + l15) * 32 + quad * 8];
#pragma unroll
    for (int mi = 0; mi < 4; mi++)
#pragma unroll
      for (int ni = 0; ni < 4; ni++)
        acc[mi][ni] = __builtin_amdgcn_mfma_f32_16x16x32_bf16(af[mi], bf[ni], acc[mi][ni], 0, 0, 0);
  }

  // epilogue: C row = bM+wm*64+mi*16+quad*4+reg, col = bN+wn*64+ni*16+l15
#pragma unroll
  for (int mi = 0; mi < 4; mi++) {
#pragma unroll
    for (int ni = 0; ni < 4; ni++) {
      const int n_col = bN + wn * 64 + ni * 16 + l15;
      const int m0 = bM + wm * 64 + mi * 16 + quad * 4;  // multiple of 4; all 4 rows same batch
      const float bv = bias[n_col];
      const int s = n_col >> 10;          // wave-uniform (16-col groups aligned)
      const int rem = n_col & 1023;
      const int h = rem >> 6, d = rem & 63;
      const int b = m0 >> 11;
      const int nn = m0 & 2047;
      const int bh = b * 16 + h;
      if (s == 2) {
        ushort4 o;
        o.x = f2bf(acc[mi][ni][0] + bv);
        o.y = f2bf(acc[mi][ni][1] + bv);
        o.z = f2bf(acc[mi][ni][2] + bv);
        o.w = f2bf(acc[mi][ni][3] + bv);
        *(ushort4*)&vt[((size_t)bh * 64 + d) * 2048 + nn] = o;
      } else {
        unsigned short* dst = (s == 0) ? qb : kb;
        const float scale = (s == 0) ? 0.125f : 1.0f;
#pragma unroll
        for (int r = 0; r < 4; r++) {
          float v = (acc[mi][ni][r] + bv) * scale;
          dst[((size_t)bh * 2048 + nn + r) * 64 + d] = f2bf(v);
        }
      }
    }
  }
}

// ---------------- Flash attention: per (bh, 64 q-rows) block ----------------
// Double-buffered K/V LDS via global_load_lds: ONE barrier per iteration; DMA for tile kt+1
// overlaps compute on tile kt (the barrier's vmcnt(0) drain only pays the remainder).
// Unpadded LDS (DMA requirement); conflicts broken by XOR swizzle on the global source
// address (LDS row r group g holds source group g^(r&7); fragment read offset is
// lane-constant since fragment rows == l15 mod 8).
__global__ __launch_bounds__(256, 4) void attn(const unsigned short* __restrict__ qb,
                                               const unsigned short* __restrict__ kb,
                                               const unsigned short* __restrict__ vt,
                                               unsigned short* __restrict__ ob) {
  __shared__ unsigned short Ks[2][64 * 64];   // [buf][key][d-group swizzled]
  __shared__ unsigned short Vs[2][64 * 64];   // [buf][d][key-group swizzled]
  __shared__ unsigned short Ps[4][16 * 72];
  const int bh = blockIdx.y;
  const int q0 = blockIdx.x * 64;
  const int t = threadIdx.x, lane = t & 63, wv = t >> 6;
  const int quad = lane >> 4, l15 = lane & 15;
  const int ri = lane >> 3;    // 0..7: row within an 8-row DMA group
  const int g = lane & 7;      // 0..7: 16B group within a row
  const int sg = g ^ ri;       // swizzled source group

  // Q fragments direct from global: A[m=l15][k=quad*8+j], rows q0+wv*16+l15
  const size_t qbase = ((size_t)bh * 2048 + q0 + wv * 16 + l15) * 64 + quad * 8;
  const bf16x8 qf0 = *(const bf16x8*)&qb[qbase];
  const bf16x8 qf1 = *(const bf16x8*)&qb[qbase + 32];

  // DMA sources: wave wv loads rows [wv*16, wv*16+16) of each 64x64 tile (two 8-row groups)
  const int rb0 = wv * 16;
  const int rb1 = wv * 16 + 8;
  const unsigned short* kS0 = kb + ((size_t)bh * 2048 + rb0 + ri) * 64 + sg * 8;  // +kt*4096
  const unsigned short* kS1 = kb + ((size_t)bh * 2048 + rb1 + ri) * 64 + sg * 8;
  const unsigned short* vS0 = vt + ((size_t)bh * 64 + rb0 + ri) * 2048 + sg * 8;  // +kt*64
  const unsigned short* vS1 = vt + ((size_t)bh * 64 + rb1 + ri) * 2048 + sg * 8;

  // lane-constant swizzled fragment read offsets (elements)
  const int o0 = (quad ^ (l15 & 7)) * 8;
  const int o1 = ((quad + 4) ^ (l15 & 7)) * 8;

  f32x4 acco[4];
#pragma unroll
  for (int i = 0; i < 4; i++) acco[i] = f32x4{0.f, 0.f, 0.f, 0.f};
  float li[4] = {0.f, 0.f, 0.f, 0.f};

  // prologue: DMA tile 0 into buffer 0
  __builtin_amdgcn_global_load_lds(
      (const __attribute__((address_space(1))) void*)(kS0),
      (__attribute__((address_space(3))) void*)(&Ks[0][rb0 * 64]), 16, 0, 0);
  __builtin_amdgcn_global_load_lds(
      (const __attribute__((address_space(1))) void*)(kS1),
      (__attribute__((address_space(3))) void*)(&Ks[0][rb1 * 64]), 16, 0, 0);
  __builtin_amdgcn_global_load_lds(
      (const __attribute__((address_space(1))) void*)(vS0),
      (__attribute__((address_space(3))) void*)(&Vs[0][rb0 * 64]), 16, 0, 0);
  __builtin_amdgcn_global_load_lds(
      (const __attribute__((address_space(1))) void*)(vS1),
      (__attribute__((address_space(3))) void*)(&Vs[0][rb1 * 64]), 16, 0, 0);

  for (int kt = 0; kt < 32; ++kt) {
    __syncthreads();  // drains DMA for buf[kt&1]; syncs readers of buf[(kt+1)&1]
    const int cur = kt & 1;
    const int nxt = cur ^ 1;
    const int ktn = (kt < 31) ? kt + 1 : kt;  // tile 31 redundantly re-fetched, branchless
    __builtin_amdgcn_global_load_lds(
        (const __attribute__((address_space(1))) void*)(kS0 + (size_t)ktn * 4096),
        (__attribute__((address_space(3))) void*)(&Ks[nxt][rb0 * 64]), 16, 0, 0);
    __builtin_amdgcn_global_load_lds(
        (const __attribute__((address_space(1))) void*)(kS1 + (size_t)ktn * 4096),
        (__attribute__((address_space(3))) void*)(&Ks[nxt][rb1 * 64]), 16, 0, 0);
    __builtin_amdgcn_global_load_lds(
        (const __attribute__((address_space(1))) void*)(vS0 + (size_t)ktn * 64),
        (__attribute__((address_space(3))) void*)(&Vs[nxt][rb0 * 64]), 16, 0, 0);
    __builtin_amdgcn_global_load_lds(
        (const __attribute__((address_space(1))) void*)(vS1 + (size_t)ktn * 64),
        (__attribute__((address_space(3))) void*)(&Vs[nxt][rb1 * 64]), 16, 0, 0);

    // S = Q K^T (1/8 scale folded into Q). C layout: row(q)=quad*4+r, col(key)=ct*16+l15
    f32x4 s[4];
#pragma unroll
    for (int ct = 0; ct < 4; ct++) {
      const int row = (ct * 16 + l15) * 64;
      bf16x8 kf0 = *(const bf16x8*)&Ks[cur][row + o0];
      bf16x8 kf1 = *(const bf16x8*)&Ks[cur][row + o1];
      f32x4 z = f32x4{0.f, 0.f, 0.f, 0.f};
      z = __builtin_amdgcn_mfma_f32_16x16x32_bf16(qf0, kf0, z, 0, 0, 0);
      s[ct] = __builtin_amdgcn_mfma_f32_16x16x32_bf16(qf1, kf1, z, 0, 0, 0);
    }

    // p = exp(s); per-lane partial l; stage P in A-layout via per-wave LDS
#pragma unroll
    for (int ct = 0; ct < 4; ct++)
#pragma unroll
      for (int r = 0; r < 4; r++) {
        float p = __expf(s[ct][r]);
        li[r] += p;
        Ps[wv][(quad * 4 + r) * 72 + ct * 16 + l15] = f2bf(p);
      }

    bf16x8 pf0 = *(const bf16x8*)&Ps[wv][l15 * 72 + quad * 8];
    bf16x8 pf1 = *(const bf16x8*)&Ps[wv][l15 * 72 + 32 + quad * 8];
#pragma unroll
    for (int ni = 0; ni < 4; ni++) {
      const int row = (ni * 16 + l15) * 64;
      bf16x8 vf0 = *(const bf16x8*)&Vs[cur][row + o0];
      bf16x8 vf1 = *(const bf16x8*)&Vs[cur][row + o1];
      acco[ni] = __builtin_amdgcn_mfma_f32_16x16x32_bf16(pf0, vf0, acco[ni], 0, 0, 0);
      acco[ni] = __builtin_amdgcn_mfma_f32_16x16x32_bf16(pf1, vf1, acco[ni], 0, 0, 0);
    }
  }

  // deferred l reduction across the 16 lanes holding each q-row's key slices
#pragma unroll
  for (int off = 1; off < 16; off <<= 1)
#pragma unroll
    for (int r = 0; r < 4; r++) li[r] += __shfl_xor(li[r], off);

  const int b = bh >> 4, h = bh & 15;
  float inv[4];
#pragma unroll
  for (int r = 0; r < 4; r++) inv[r] = 1.0f / li[r];
#pragma unroll
  for (int ni = 0; ni < 4; ni++)
#pragma unroll
    for (int r = 0; r < 4; r++) {
      size_t row = (size_t)b * 2048 + q0 + wv * 16 + quad * 4 + r;
      ob[row * 1024 + h * 64 + ni * 16 + l15] = f2bf(acco[ni][r] * inv[r]);
    }
}

// ---------------- Output GEMM: bf16 ob [8192,1024] @ f32 w_out [1024,1024]^T + bias -> fp32 ----------------
__global__ __launch_bounds__(256, 2) void gemm_out(
    const unsigned short* __restrict__ A,    // attn out bf16 [8192][1024]
    const float* __restrict__ Bw,            // w_out f32 [1024][1024]
    const float* __restrict__ bias,          // [1024]
    float* __restrict__ out) {
  __shared__ unsigned short As[128 * 32];
  __shared__ unsigned short Bs[128 * 32];
  const int t = threadIdx.x;
  const int lane = t & 63;
  const int wv = t >> 6;
  const int wm = wv >> 1, wn = wv & 1;
  const int quad = lane >> 4, l15 = lane & 15;
  const int bM = blockIdx.y * 128;
  const int bN = blockIdx.x * 128;
  const int r0 = t >> 2;
  const int c0 = (t & 3) * 8;

  f32x4 acc[4][4];
#pragma unroll
  for (int i = 0; i < 4; i++)
#pragma unroll
    for (int j = 0; j < 4; j++) acc[i][j] = f32x4{0.f, 0.f, 0.f, 0.f};

  const unsigned short* aS0 = A + (size_t)(bM + r0) * 1024 + c0;
  const unsigned short* aS1 = A + (size_t)(bM + 64 + r0) * 1024 + c0;
  const size_t bR0 = (size_t)(bN + r0) * 1024 + c0;
  const size_t bR1 = (size_t)(bN + 64 + r0) * 1024 + c0;

  for (int kt = 0; kt < 32; ++kt) {
    const int k0 = kt * 32;
    __syncthreads();
    __builtin_amdgcn_global_load_lds(
        (const __attribute__((address_space(1))) void*)(aS0 + k0),
        (__attribute__((address_space(3))) void*)(&As[r0 * 32 + c0]), 16, 0, 0);
    __builtin_amdgcn_global_load_lds(
        (const __attribute__((address_space(1))) void*)(aS1 + k0),
        (__attribute__((address_space(3))) void*)(&As[(64 + r0) * 32 + c0]), 16, 0, 0);
    float4 b00 = *(const float4*)&Bw[bR0 + k0];
    float4 b01 = *(const float4*)&Bw[bR0 + k0 + 4];
    float4 b10 = *(const float4*)&Bw[bR1 + k0];
    float4 b11 = *(const float4*)&Bw[bR1 + k0 + 4];
    *(ushort4*)&Bs[r0 * 32 + c0] = cvt4(b00);
    *(ushort4*)&Bs[r0 * 32 + c0 + 4] = cvt4(b01);
    *(ushort4*)&Bs[(64 + r0) * 32 + c0] = cvt4(b10);
    *(ushort4*)&Bs[(64 + r0) * 32 + c0 + 4] = cvt4(b11);
    __syncthreads();

    bf16x8 af[4], bf[4];
#pragma unroll
    for (int mi = 0; mi < 4; mi++)
      af[mi] = *(const bf16x8*)&As[(wm * 64 + mi * 16 + l15) * 32 + quad * 8];
#pragma unroll
    for (int ni = 0; ni < 4; ni++)
      bf[ni] = *(const bf16x8*)&Bs[(wn * 64 + ni * 16 + l15) * 32 + quad * 8];
#pragma unroll
    for (int mi = 0; mi < 4; mi++)
#pragma unroll
      for (int ni = 0; ni < 4; ni++)
        acc[mi][ni] = __builtin_amdgcn_mfma_f32_16x16x32_bf16(af[mi], bf[ni], acc[mi][ni], 0, 0, 0);
  }

#pragma unroll
  for (int mi = 0; mi < 4; mi++) {
#pragma unroll
    for (int ni = 0; ni < 4; ni++) {
      const int n_col = bN + wn * 64 + ni * 16 + l15;
      const int m0 = bM + wm * 64 + mi * 16 + quad * 4;
      const float bv = bias[n_col];
#pragma unroll
      for (int r = 0; r < 4; r++)
        out[(size_t)(m0 + r) * 1024 + n_col] = acc[mi][ni][r] + bv;
    }
  }
}

extern "C" void kernel_launch(void* const* d_in, const int* in_sizes, int n_in,
                              void* d_out, int out_size, void* d_ws, size_t ws_size,
                              hipStream_t stream) {
  const float* x = (const float*)d_in[0];
  const float* w_qkv = (const float*)d_in[1];
  const float* b_qkv = (const float*)d_in[2];
  const float* w_out = (const float*)d_in[3];
  const float* b_out = (const float*)d_in[4];
  float* out = (float*)d_out;
  char* ws = (char*)d_ws;

  // ---- workspace layout: 32 MiB total ----
  // [0,16MiB)   vt : V^T [64][64][2048] bf16
  // [16,32MiB)  xb : x as bf16 (gemm_qkv A-side); dead after gemm_qkv, reused as ob
  unsigned short* vt = (unsigned short*)(ws);
  unsigned short* xb = (unsigned short*)(ws + (size_t)16 * 1024 * 1024);
  unsigned short* ob = xb;

  // ---- qb/kb live inside d_out (32 MiB): lifetime ends before gemm_out writes it ----
  unsigned short* qb = (unsigned short*)d_out;                 // 16 MiB
  unsigned short* kb = qb + (size_t)8 * 1024 * 1024;           // 16 MiB

  cvt_bf16<<<2048, 256, 0, stream>>>(x, xb, 8192 * 1024 / 4);
  gemm_qkv<<<dim3(24, 64), 256, 0, stream>>>(xb, w_qkv, b_qkv, qb, kb, vt);
  attn<<<dim3(32, 64), 256, 0, stream>>>(qb, kb, vt, ob);
  gemm_out<<<dim3(8, 64), 256, 0, stream>>>(ob, w_out, b_out, out);
}

// Round 9
// 303.001 us; speedup vs baseline: 1.2181x; 1.2181x over previous
//
#include <hip/hip_runtime.h>
#include <hip/hip_bf16.h>
#include <cstdint>
#include <cstddef>

#define NHEADS 16
#define DHEAD 64
#define BATCH 4
#define SEQ 2048
// M = 8192, D = 1024

typedef __attribute__((ext_vector_type(8))) __bf16 bf16x8;
typedef __attribute__((ext_vector_type(4))) float f32x4;

__device__ __forceinline__ unsigned short f2bf(float f) {
  union { float f; unsigned u; } v; v.f = f;
  unsigned r = v.u + 0x7FFFu + ((v.u >> 16) & 1u);  // RNE
  return (unsigned short)(r >> 16);
}

__device__ __forceinline__ ushort4 cvt4(float4 f) {
  ushort4 o;
  o.x = f2bf(f.x); o.y = f2bf(f.y); o.z = f2bf(f.z); o.w = f2bf(f.w);
  return o;
}

// ---------------- f32 -> bf16 convert (x4 vectorized) ----------------
__global__ void cvt_bf16(const float* __restrict__ in, unsigned short* __restrict__ out, int n4) {
  int i = blockIdx.x * blockDim.x + threadIdx.x;
  int stride = gridDim.x * blockDim.x;
  for (; i < n4; i += stride) {
    float4 f = ((const float4*)in)[i];
    ((ushort4*)out)[i] = cvt4(f);
  }
}

// ---------------- QKV GEMM: bf16 xb [8192,1024] @ f32 w_qkv [3072,1024]^T + bias ----------------
// A-side via global_load_lds (async DMA, no cross-barrier registers -> no spill);
// B-side f32 loads + cvt + ds_write inside the barrier window.
__global__ __launch_bounds__(256, 2) void gemm_qkv(
    const unsigned short* __restrict__ A,    // xb bf16 [8192][1024]
    const float* __restrict__ Bw,            // w_qkv f32 [3072][1024]
    const float* __restrict__ bias,          // [3072]
    unsigned short* __restrict__ qb,         // [64][2048][64]  (q pre-scaled by 1/8)
    unsigned short* __restrict__ kb,         // [64][2048][64]
    unsigned short* __restrict__ vt) {       // [64][64][2048]  (V^T)
  __shared__ unsigned short As[128 * 32];    // unpadded: DMA dest = base + lane*16B
  __shared__ unsigned short Bs[128 * 32];
  const int t = threadIdx.x;
  const int lane = t & 63;
  const int wv = t >> 6;
  const int wm = wv >> 1, wn = wv & 1;
  const int quad = lane >> 4, l15 = lane & 15;
  const int bM = blockIdx.y * 128;
  const int bN = blockIdx.x * 128;
  const int r0 = t >> 2;        // 0..63
  const int c0 = (t & 3) * 8;   // 0,8,16,24

  f32x4 acc[4][4];
#pragma unroll
  for (int i = 0; i < 4; i++)
#pragma unroll
    for (int j = 0; j < 4; j++) acc[i][j] = f32x4{0.f, 0.f, 0.f, 0.f};

  const unsigned short* aS0 = A + (size_t)(bM + r0) * 1024 + c0;        // + k0
  const unsigned short* aS1 = A + (size_t)(bM + 64 + r0) * 1024 + c0;
  const size_t bR0 = (size_t)(bN + r0) * 1024 + c0;
  const size_t bR1 = (size_t)(bN + 64 + r0) * 1024 + c0;

  for (int kt = 0; kt < 32; ++kt) {
    const int k0 = kt * 32;
    __syncthreads();  // previous iteration's LDS readers done
    __builtin_amdgcn_global_load_lds(
        (const __attribute__((address_space(1))) void*)(aS0 + k0),
        (__attribute__((address_space(3))) void*)(&As[r0 * 32 + c0]), 16, 0, 0);
    __builtin_amdgcn_global_load_lds(
        (const __attribute__((address_space(1))) void*)(aS1 + k0),
        (__attribute__((address_space(3))) void*)(&As[(64 + r0) * 32 + c0]), 16, 0, 0);
    float4 b00 = *(const float4*)&Bw[bR0 + k0];
    float4 b01 = *(const float4*)&Bw[bR0 + k0 + 4];
    float4 b10 = *(const float4*)&Bw[bR1 + k0];
    float4 b11 = *(const float4*)&Bw[bR1 + k0 + 4];
    *(ushort4*)&Bs[r0 * 32 + c0] = cvt4(b00);
    *(ushort4*)&Bs[r0 * 32 + c0 + 4] = cvt4(b01);
    *(ushort4*)&Bs[(64 + r0) * 32 + c0] = cvt4(b10);
    *(ushort4*)&Bs[(64 + r0) * 32 + c0 + 4] = cvt4(b11);
    __syncthreads();  // drains DMA (vmcnt) + LDS writes (lgkm)

    bf16x8 af[4], bf[4];
#pragma unroll
    for (int mi = 0; mi < 4; mi++)
      af[mi] = *(const bf16x8*)&As[(wm * 64 + mi * 16 + l15) * 32 + quad * 8];
#pragma unroll
    for (int ni = 0; ni < 4; ni++)
      bf[ni] = *(const bf16x8*)&Bs[(wn * 64 + ni * 16 + l15) * 32 + quad * 8];
#pragma unroll
    for (int mi = 0; mi < 4; mi++)
#pragma unroll
      for (int ni = 0; ni < 4; ni++)
        acc[mi][ni] = __builtin_amdgcn_mfma_f32_16x16x32_bf16(af[mi], bf[ni], acc[mi][ni], 0, 0, 0);
  }

  // epilogue: C row = bM+wm*64+mi*16+quad*4+reg, col = bN+wn*64+ni*16+l15
#pragma unroll
  for (int mi = 0; mi < 4; mi++) {
#pragma unroll
    for (int ni = 0; ni < 4; ni++) {
      const int n_col = bN + wn * 64 + ni * 16 + l15;
      const int m0 = bM + wm * 64 + mi * 16 + quad * 4;  // multiple of 4; all 4 rows same batch
      const float bv = bias[n_col];
      const int s = n_col >> 10;          // wave-uniform (16-col groups aligned)
      const int rem = n_col & 1023;
      const int h = rem >> 6, d = rem & 63;
      const int b = m0 >> 11;
      const int nn = m0 & 2047;
      const int bh = b * 16 + h;
      if (s == 2) {
        ushort4 o;
        o.x = f2bf(acc[mi][ni][0] + bv);
        o.y = f2bf(acc[mi][ni][1] + bv);
        o.z = f2bf(acc[mi][ni][2] + bv);
        o.w = f2bf(acc[mi][ni][3] + bv);
        *(ushort4*)&vt[((size_t)bh * 64 + d) * 2048 + nn] = o;
      } else {
        unsigned short* dst = (s == 0) ? qb : kb;
        const float scale = (s == 0) ? 0.125f : 1.0f;
#pragma unroll
        for (int r = 0; r < 4; r++) {
          float v = (acc[mi][ni][r] + bv) * scale;
          dst[((size_t)bh * 2048 + nn + r) * 64 + d] = f2bf(v);
        }
      }
    }
  }
}

// ---------------- Flash attention: per (bh, 128 q-rows) block ----------------
// R7 single-buffer barrier structure (proven; R8's dbuf cost occupancy and lost).
// Each wave handles 32 q-rows (2 groups of 16) against the shared 64-key K/V tile:
// K/V fragment LDS reads amortized over 2x the MFMA (1.125 -> 0.625 b128/MFMA).
// Unpadded LDS (DMA requirement); XOR swizzle on global source breaks bank conflicts.
__global__ __launch_bounds__(256, 4) void attn(const unsigned short* __restrict__ qb,
                                               const unsigned short* __restrict__ kb,
                                               const unsigned short* __restrict__ vt,
                                               unsigned short* __restrict__ ob) {
  __shared__ unsigned short Ks[64 * 64];      // [key][d-group swizzled]
  __shared__ unsigned short Vs[64 * 64];      // [d][key-group swizzled]
  __shared__ unsigned short Ps[4][2][16 * 72];
  const int bh = blockIdx.y;
  const int q0 = blockIdx.x * 128;
  const int t = threadIdx.x, lane = t & 63, wv = t >> 6;
  const int quad = lane >> 4, l15 = lane & 15;
  const int ri = lane >> 3;    // 0..7: row within an 8-row DMA group
  const int g = lane & 7;      // 0..7: 16B group within a row
  const int sg = g ^ ri;       // swizzled source group

  // Q fragments for both 16-row groups, direct from global (A-layout)
  bf16x8 qf0[2], qf1[2];
#pragma unroll
  for (int grp = 0; grp < 2; grp++) {
    const size_t qbase = ((size_t)bh * 2048 + q0 + wv * 32 + grp * 16 + l15) * 64 + quad * 8;
    qf0[grp] = *(const bf16x8*)&qb[qbase];
    qf1[grp] = *(const bf16x8*)&qb[qbase + 32];
  }

  // DMA sources: wave wv loads rows [wv*16, wv*16+16) of each 64x64 tile
  const int rb0 = wv * 16;
  const int rb1 = wv * 16 + 8;
  const unsigned short* kS0 = kb + ((size_t)bh * 2048 + rb0 + ri) * 64 + sg * 8;  // +kt*4096
  const unsigned short* kS1 = kb + ((size_t)bh * 2048 + rb1 + ri) * 64 + sg * 8;
  const unsigned short* vS0 = vt + ((size_t)bh * 64 + rb0 + ri) * 2048 + sg * 8;  // +kt*64
  const unsigned short* vS1 = vt + ((size_t)bh * 64 + rb1 + ri) * 2048 + sg * 8;

  // lane-constant swizzled fragment read offsets (elements)
  const int o0 = (quad ^ (l15 & 7)) * 8;
  const int o1 = ((quad + 4) ^ (l15 & 7)) * 8;

  f32x4 acco[2][4];
#pragma unroll
  for (int grp = 0; grp < 2; grp++)
#pragma unroll
    for (int i = 0; i < 4; i++) acco[grp][i] = f32x4{0.f, 0.f, 0.f, 0.f};
  float li[2][4] = {{0.f, 0.f, 0.f, 0.f}, {0.f, 0.f, 0.f, 0.f}};

  for (int kt = 0; kt < 32; ++kt) {
    __syncthreads();  // previous iteration's readers done before DMA overwrites
    __builtin_amdgcn_global_load_lds(
        (const __attribute__((address_space(1))) void*)(kS0 + (size_t)kt * 4096),
        (__attribute__((address_space(3))) void*)(&Ks[rb0 * 64]), 16, 0, 0);
    __builtin_amdgcn_global_load_lds(
        (const __attribute__((address_space(1))) void*)(kS1 + (size_t)kt * 4096),
        (__attribute__((address_space(3))) void*)(&Ks[rb1 * 64]), 16, 0, 0);
    __builtin_amdgcn_global_load_lds(
        (const __attribute__((address_space(1))) void*)(vS0 + (size_t)kt * 64),
        (__attribute__((address_space(3))) void*)(&Vs[rb0 * 64]), 16, 0, 0);
    __builtin_amdgcn_global_load_lds(
        (const __attribute__((address_space(1))) void*)(vS1 + (size_t)kt * 64),
        (__attribute__((address_space(3))) void*)(&Vs[rb1 * 64]), 16, 0, 0);
    __syncthreads();  // vmcnt(0) drain before barrier makes DMA results visible

    // S = Q K^T (1/8 folded into Q). kf fragments reused across both q-groups.
    f32x4 s[2][4];
#pragma unroll
    for (int ct = 0; ct < 4; ct++) {
      const int row = (ct * 16 + l15) * 64;
      bf16x8 kf0 = *(const bf16x8*)&Ks[row + o0];
      bf16x8 kf1 = *(const bf16x8*)&Ks[row + o1];
#pragma unroll
      for (int grp = 0; grp < 2; grp++) {
        f32x4 z = f32x4{0.f, 0.f, 0.f, 0.f};
        z = __builtin_amdgcn_mfma_f32_16x16x32_bf16(qf0[grp], kf0, z, 0, 0, 0);
        s[grp][ct] = __builtin_amdgcn_mfma_f32_16x16x32_bf16(qf1[grp], kf1, z, 0, 0, 0);
      }
    }

    // p = exp(s); per-lane partial l; packed bf16 cvt; stage P in A-layout
#pragma unroll
    for (int grp = 0; grp < 2; grp++)
#pragma unroll
      for (int ct = 0; ct < 4; ct++) {
        float p0 = __expf(s[grp][ct][0]);
        float p1 = __expf(s[grp][ct][1]);
        float p2 = __expf(s[grp][ct][2]);
        float p3 = __expf(s[grp][ct][3]);
        li[grp][0] += p0; li[grp][1] += p1; li[grp][2] += p2; li[grp][3] += p3;
        union { __hip_bfloat162 h; ushort2 u; } c01, c23;
        c01.h = __float22bfloat162_rn(make_float2(p0, p1));
        c23.h = __float22bfloat162_rn(make_float2(p2, p3));
        unsigned short* pbase = &Ps[wv][grp][(quad * 4) * 72 + ct * 16 + l15];
        pbase[0] = c01.u.x;
        pbase[72] = c01.u.y;
        pbase[144] = c23.u.x;
        pbase[216] = c23.u.y;
      }

    bf16x8 pf0[2], pf1[2];
#pragma unroll
    for (int grp = 0; grp < 2; grp++) {
      pf0[grp] = *(const bf16x8*)&Ps[wv][grp][l15 * 72 + quad * 8];
      pf1[grp] = *(const bf16x8*)&Ps[wv][grp][l15 * 72 + 32 + quad * 8];
    }
    // PV: vf fragments reused across both q-groups
#pragma unroll
    for (int ni = 0; ni < 4; ni++) {
      const int row = (ni * 16 + l15) * 64;
      bf16x8 vf0 = *(const bf16x8*)&Vs[row + o0];
      bf16x8 vf1 = *(const bf16x8*)&Vs[row + o1];
#pragma unroll
      for (int grp = 0; grp < 2; grp++) {
        acco[grp][ni] = __builtin_amdgcn_mfma_f32_16x16x32_bf16(pf0[grp], vf0, acco[grp][ni], 0, 0, 0);
        acco[grp][ni] = __builtin_amdgcn_mfma_f32_16x16x32_bf16(pf1[grp], vf1, acco[grp][ni], 0, 0, 0);
      }
    }
  }

  // deferred l reduction across the 16 lanes holding each q-row's key slices
#pragma unroll
  for (int off = 1; off < 16; off <<= 1)
#pragma unroll
    for (int grp = 0; grp < 2; grp++)
#pragma unroll
      for (int r = 0; r < 4; r++) li[grp][r] += __shfl_xor(li[grp][r], off);

  const int b = bh >> 4, h = bh & 15;
#pragma unroll
  for (int grp = 0; grp < 2; grp++) {
    float inv[4];
#pragma unroll
    for (int r = 0; r < 4; r++) inv[r] = 1.0f / li[grp][r];
#pragma unroll
    for (int ni = 0; ni < 4; ni++)
#pragma unroll
      for (int r = 0; r < 4; r++) {
        size_t row = (size_t)b * 2048 + q0 + wv * 32 + grp * 16 + quad * 4 + r;
        ob[row * 1024 + h * 64 + ni * 16 + l15] = f2bf(acco[grp][ni][r] * inv[r]);
      }
  }
}

// ---------------- Output GEMM: bf16 ob [8192,1024] @ f32 w_out [1024,1024]^T + bias -> fp32 ----------------
__global__ __launch_bounds__(256, 2) void gemm_out(
    const unsigned short* __restrict__ A,    // attn out bf16 [8192][1024]
    const float* __restrict__ Bw,            // w_out f32 [1024][1024]
    const float* __restrict__ bias,          // [1024]
    float* __restrict__ out) {
  __shared__ unsigned short As[128 * 32];
  __shared__ unsigned short Bs[128 * 32];
  const int t = threadIdx.x;
  const int lane = t & 63;
  const int wv = t >> 6;
  const int wm = wv >> 1, wn = wv & 1;
  const int quad = lane >> 4, l15 = lane & 15;
  const int bM = blockIdx.y * 128;
  const int bN = blockIdx.x * 128;
  const int r0 = t >> 2;
  const int c0 = (t & 3) * 8;

  f32x4 acc[4][4];
#pragma unroll
  for (int i = 0; i < 4; i++)
#pragma unroll
    for (int j = 0; j < 4; j++) acc[i][j] = f32x4{0.f, 0.f, 0.f, 0.f};

  const unsigned short* aS0 = A + (size_t)(bM + r0) * 1024 + c0;
  const unsigned short* aS1 = A + (size_t)(bM + 64 + r0) * 1024 + c0;
  const size_t bR0 = (size_t)(bN + r0) * 1024 + c0;
  const size_t bR1 = (size_t)(bN + 64 + r0) * 1024 + c0;

  for (int kt = 0; kt < 32; ++kt) {
    const int k0 = kt * 32;
    __syncthreads();
    __builtin_amdgcn_global_load_lds(
        (const __attribute__((address_space(1))) void*)(aS0 + k0),
        (__attribute__((address_space(3))) void*)(&As[r0 * 32 + c0]), 16, 0, 0);
    __builtin_amdgcn_global_load_lds(
        (const __attribute__((address_space(1))) void*)(aS1 + k0),
        (__attribute__((address_space(3))) void*)(&As[(64 + r0) * 32 + c0]), 16, 0, 0);
    float4 b00 = *(const float4*)&Bw[bR0 + k0];
    float4 b01 = *(const float4*)&Bw[bR0 + k0 + 4];
    float4 b10 = *(const float4*)&Bw[bR1 + k0];
    float4 b11 = *(const float4*)&Bw[bR1 + k0 + 4];
    *(ushort4*)&Bs[r0 * 32 + c0] = cvt4(b00);
    *(ushort4*)&Bs[r0 * 32 + c0 + 4] = cvt4(b01);
    *(ushort4*)&Bs[(64 + r0) * 32 + c0] = cvt4(b10);
    *(ushort4*)&Bs[(64 + r0) * 32 + c0 + 4] = cvt4(b11);
    __syncthreads();

    bf16x8 af[4], bf[4];
#pragma unroll
    for (int mi = 0; mi < 4; mi++)
      af[mi] = *(const bf16x8*)&As[(wm * 64 + mi * 16 + l15) * 32 + quad * 8];
#pragma unroll
    for (int ni = 0; ni < 4; ni++)
      bf[ni] = *(const bf16x8*)&Bs[(wn * 64 + ni * 16 + l15) * 32 + quad * 8];
#pragma unroll
    for (int mi = 0; mi < 4; mi++)
#pragma unroll
      for (int ni = 0; ni < 4; ni++)
        acc[mi][ni] = __builtin_amdgcn_mfma_f32_16x16x32_bf16(af[mi], bf[ni], acc[mi][ni], 0, 0, 0);
  }

#pragma unroll
  for (int mi = 0; mi < 4; mi++) {
#pragma unroll
    for (int ni = 0; ni < 4; ni++) {
      const int n_col = bN + wn * 64 + ni * 16 + l15;
      const int m0 = bM + wm * 64 + mi * 16 + quad * 4;
      const float bv = bias[n_col];
#pragma unroll
      for (int r = 0; r < 4; r++)
        out[(size_t)(m0 + r) * 1024 + n_col] = acc[mi][ni][r] + bv;
    }
  }
}

extern "C" void kernel_launch(void* const* d_in, const int* in_sizes, int n_in,
                              void* d_out, int out_size, void* d_ws, size_t ws_size,
                              hipStream_t stream) {
  const float* x = (const float*)d_in[0];
  const float* w_qkv = (const float*)d_in[1];
  const float* b_qkv = (const float*)d_in[2];
  const float* w_out = (const float*)d_in[3];
  const float* b_out = (const float*)d_in[4];
  float* out = (float*)d_out;
  char* ws = (char*)d_ws;

  // ---- workspace layout: 32 MiB total ----
  // [0,16MiB)   vt : V^T [64][64][2048] bf16
  // [16,32MiB)  xb : x as bf16 (gemm_qkv A-side); dead after gemm_qkv, reused as ob
  unsigned short* vt = (unsigned short*)(ws);
  unsigned short* xb = (unsigned short*)(ws + (size_t)16 * 1024 * 1024);
  unsigned short* ob = xb;

  // ---- qb/kb live inside d_out (32 MiB): lifetime ends before gemm_out writes it ----
  unsigned short* qb = (unsigned short*)d_out;                 // 16 MiB
  unsigned short* kb = qb + (size_t)8 * 1024 * 1024;           // 16 MiB

  cvt_bf16<<<2048, 256, 0, stream>>>(x, xb, 8192 * 1024 / 4);
  gemm_qkv<<<dim3(24, 64), 256, 0, stream>>>(xb, w_qkv, b_qkv, qb, kb, vt);
  attn<<<dim3(16, 64), 256, 0, stream>>>(qb, kb, vt, ob);
  gemm_out<<<dim3(8, 64), 256, 0, stream>>>(ob, w_out, b_out, out);
}